// Round 2
// baseline (810.783 us; speedup 1.0000x reference)
//
#include <hip/hip_runtime.h>
#include <math.h>

#define NPTS 400000
#define NBATCH 8
#define K_OUT 64
#define IDX_SENTINEL 0x7fffffff

// comparator: (value desc, index asc) — matches jax.lax.top_k tie-breaking
__device__ __forceinline__ bool better(float av, int ai, float bv, int bi) {
    return (av > bv) || (av == bv && ai < bi);
}

__device__ __forceinline__ void cmp_swap(float& v, int& i, int j, bool keepBetter) {
    float ov = __shfl_xor(v, j);
    int   oi = __shfl_xor(i, j);
    bool ob = better(ov, oi, v, i);
    if (keepBetter ? ob : !ob) { v = ov; i = oi; }
}

// Maintain per-wave top-64 (1 entry/lane, sorted descending by comparator).
__device__ __forceinline__ void wave_topk_insert(float& bv, int& bi, float nv, int ni, int lane) {
    float tv = __shfl(bv, 63);
    int   ti = __shfl(bi, 63);
    if (__ballot(better(nv, ni, tv, ti)) == 0ULL) return;
#pragma unroll
    for (int k = 2; k <= 64; k <<= 1) {
#pragma unroll
        for (int j = k >> 1; j > 0; j >>= 1) {
            bool keepBetter = (((lane & k) == 0) == ((lane & j) == 0));
            cmp_swap(nv, ni, j, keepBetter);
        }
    }
    float rv = __shfl(nv, lane ^ 63);
    int   ri = __shfl(ni, lane ^ 63);
    if (better(rv, ri, bv, bi)) { bv = rv; bi = ri; }
#pragma unroll
    for (int j = 32; j > 0; j >>= 1) cmp_swap(bv, bi, j, (lane & j) == 0);
}

__global__ __launch_bounds__(256) void mlp_score_topk_k1(
    const float* __restrict__ X,
    const float* __restrict__ W1, const float* __restrict__ b1,
    const float* __restrict__ W2, const float* __restrict__ b2,
    const float* __restrict__ W3, const float* __restrict__ b3,
    int2* __restrict__ cand, int ppw)
{
    __shared__ float w1t[32 * 16];   // [c][o], rows 64B-aligned for float4 reads
    __shared__ float w2t[16 * 8];    // [c][o]
    __shared__ float smallw[33];     // b1[0:16], b2[16:24], w3[24:32], b3[32]

    int t = threadIdx.x;
    for (int idx = t; idx < 512; idx += 256) w1t[idx] = W1[(idx & 15) * 32 + (idx >> 4)];
    if (t < 128) w2t[t] = W2[(t & 7) * 16 + (t >> 3)];
    if (t < 16)       smallw[t] = b1[t];
    else if (t < 24)  smallw[t] = b2[t - 16];
    else if (t < 32)  smallw[t] = W3[t - 24];
    else if (t == 32) smallw[32] = b3[0];
    __syncthreads();

    int b = blockIdx.y;
    int wave = blockIdx.x * 4 + (t >> 6);
    int lane = t & 63;
    const float* Xb = X + (size_t)b * 32 * NPTS;

    float bv = -INFINITY;
    int   bi = IDX_SENTINEL;

    int riters = ppw >> 8;           // 256 points per r-iter
    int waveStart = wave * ppw;

#pragma unroll 1
    for (int r = 0; r < riters; ++r) {
        int n = waveStart + r * 256 + lane * 4;   // quad start; NPTS % 4 == 0
        float z0 = -INFINITY, z1 = -INFINITY, z2 = -INFINITY, z3 = -INFINITY;
        bool valid = (n < NPTS);
        if (valid) {
            float4 a1[16];
#pragma unroll
            for (int o = 0; o < 16; ++o) a1[o] = make_float4(0.f, 0.f, 0.f, 0.f);
            // layer 1: channel blocks of 8 — batch 8 global float4 loads in flight
#pragma unroll
            for (int cb = 0; cb < 4; ++cb) {
                float4 x[8];
#pragma unroll
                for (int j = 0; j < 8; ++j)
                    x[j] = *reinterpret_cast<const float4*>(Xb + (size_t)(cb * 8 + j) * NPTS + n);
#pragma unroll
                for (int j = 0; j < 8; ++j) {
                    int c = cb * 8 + j;
#pragma unroll
                    for (int q = 0; q < 4; ++q) {
                        float4 w = *reinterpret_cast<const float4*>(&w1t[c * 16 + q * 4]);
                        a1[q*4+0].x = fmaf(w.x, x[j].x, a1[q*4+0].x);
                        a1[q*4+0].y = fmaf(w.x, x[j].y, a1[q*4+0].y);
                        a1[q*4+0].z = fmaf(w.x, x[j].z, a1[q*4+0].z);
                        a1[q*4+0].w = fmaf(w.x, x[j].w, a1[q*4+0].w);
                        a1[q*4+1].x = fmaf(w.y, x[j].x, a1[q*4+1].x);
                        a1[q*4+1].y = fmaf(w.y, x[j].y, a1[q*4+1].y);
                        a1[q*4+1].z = fmaf(w.y, x[j].z, a1[q*4+1].z);
                        a1[q*4+1].w = fmaf(w.y, x[j].w, a1[q*4+1].w);
                        a1[q*4+2].x = fmaf(w.z, x[j].x, a1[q*4+2].x);
                        a1[q*4+2].y = fmaf(w.z, x[j].y, a1[q*4+2].y);
                        a1[q*4+2].z = fmaf(w.z, x[j].z, a1[q*4+2].z);
                        a1[q*4+2].w = fmaf(w.z, x[j].w, a1[q*4+2].w);
                        a1[q*4+3].x = fmaf(w.w, x[j].x, a1[q*4+3].x);
                        a1[q*4+3].y = fmaf(w.w, x[j].y, a1[q*4+3].y);
                        a1[q*4+3].z = fmaf(w.w, x[j].z, a1[q*4+3].z);
                        a1[q*4+3].w = fmaf(w.w, x[j].w, a1[q*4+3].w);
                    }
                }
            }
            // layer 2 (16->8) + ReLU on layer-1 outputs
            float4 a2[8];
#pragma unroll
            for (int o = 0; o < 8; ++o) a2[o] = make_float4(0.f, 0.f, 0.f, 0.f);
#pragma unroll
            for (int c = 0; c < 16; ++c) {
                float bb = smallw[c];
                float4 h = a1[c];
                h.x = fmaxf(h.x + bb, 0.f);
                h.y = fmaxf(h.y + bb, 0.f);
                h.z = fmaxf(h.z + bb, 0.f);
                h.w = fmaxf(h.w + bb, 0.f);
                float4 w0 = *reinterpret_cast<const float4*>(&w2t[c * 8]);
                float4 w1v = *reinterpret_cast<const float4*>(&w2t[c * 8 + 4]);
                a2[0].x = fmaf(w0.x, h.x, a2[0].x); a2[0].y = fmaf(w0.x, h.y, a2[0].y);
                a2[0].z = fmaf(w0.x, h.z, a2[0].z); a2[0].w = fmaf(w0.x, h.w, a2[0].w);
                a2[1].x = fmaf(w0.y, h.x, a2[1].x); a2[1].y = fmaf(w0.y, h.y, a2[1].y);
                a2[1].z = fmaf(w0.y, h.z, a2[1].z); a2[1].w = fmaf(w0.y, h.w, a2[1].w);
                a2[2].x = fmaf(w0.z, h.x, a2[2].x); a2[2].y = fmaf(w0.z, h.y, a2[2].y);
                a2[2].z = fmaf(w0.z, h.z, a2[2].z); a2[2].w = fmaf(w0.z, h.w, a2[2].w);
                a2[3].x = fmaf(w0.w, h.x, a2[3].x); a2[3].y = fmaf(w0.w, h.y, a2[3].y);
                a2[3].z = fmaf(w0.w, h.z, a2[3].z); a2[3].w = fmaf(w0.w, h.w, a2[3].w);
                a2[4].x = fmaf(w1v.x, h.x, a2[4].x); a2[4].y = fmaf(w1v.x, h.y, a2[4].y);
                a2[4].z = fmaf(w1v.x, h.z, a2[4].z); a2[4].w = fmaf(w1v.x, h.w, a2[4].w);
                a2[5].x = fmaf(w1v.y, h.x, a2[5].x); a2[5].y = fmaf(w1v.y, h.y, a2[5].y);
                a2[5].z = fmaf(w1v.y, h.z, a2[5].z); a2[5].w = fmaf(w1v.y, h.w, a2[5].w);
                a2[6].x = fmaf(w1v.z, h.x, a2[6].x); a2[6].y = fmaf(w1v.z, h.y, a2[6].y);
                a2[6].z = fmaf(w1v.z, h.z, a2[6].z); a2[6].w = fmaf(w1v.z, h.w, a2[6].w);
                a2[7].x = fmaf(w1v.w, h.x, a2[7].x); a2[7].y = fmaf(w1v.w, h.y, a2[7].y);
                a2[7].z = fmaf(w1v.w, h.z, a2[7].z); a2[7].w = fmaf(w1v.w, h.w, a2[7].w);
            }
            // layer 3 (8->1); softplus monotone -> rank by pre-activation
            float4 zacc = make_float4(0.f, 0.f, 0.f, 0.f);
#pragma unroll
            for (int c = 0; c < 8; ++c) {
                float bb = smallw[16 + c];
                float4 h = a2[c];
                h.x = fmaxf(h.x + bb, 0.f);
                h.y = fmaxf(h.y + bb, 0.f);
                h.z = fmaxf(h.z + bb, 0.f);
                h.w = fmaxf(h.w + bb, 0.f);
                float w = smallw[24 + c];
                zacc.x = fmaf(w, h.x, zacc.x);
                zacc.y = fmaf(w, h.y, zacc.y);
                zacc.z = fmaf(w, h.z, zacc.z);
                zacc.w = fmaf(w, h.w, zacc.w);
            }
            float b3v = smallw[32];
            z0 = zacc.x + b3v; z1 = zacc.y + b3v; z2 = zacc.z + b3v; z3 = zacc.w + b3v;
        }
        int i0 = valid ? (n + 0) : IDX_SENTINEL;
        int i1 = valid ? (n + 1) : IDX_SENTINEL;
        int i2 = valid ? (n + 2) : IDX_SENTINEL;
        int i3 = valid ? (n + 3) : IDX_SENTINEL;
        wave_topk_insert(bv, bi, z0, i0, lane);
        wave_topk_insert(bv, bi, z1, i1, lane);
        wave_topk_insert(bv, bi, z2, i2, lane);
        wave_topk_insert(bv, bi, z3, i3, lane);
    }

    cand[((size_t)b * gridDim.x * 4 + wave) * 64 + lane] = make_int2(__float_as_int(bv), bi);
}

// stage A: 16 blocks/batch, 4 waves each -> reduce lpb lists to 16 lists/batch
__global__ __launch_bounds__(256) void topk_merge_k2a(
    const int2* __restrict__ cand, int2* __restrict__ cand2, int lpb)
{
    __shared__ int2 sbuf[4 * 64];
    int b = blockIdx.y;
    int bk = blockIdx.x;          // 0..15
    int t = threadIdx.x;
    int w = t >> 6, lane = t & 63;
    const int2* cb = cand + (size_t)b * lpb * 64;

    float bv = -INFINITY;
    int   bi = IDX_SENTINEL;
    int slot = bk * 4 + w;        // 0..63
#pragma unroll 1
    for (int L = slot; L < lpb; L += 64) {
        int2 p = cb[(size_t)L * 64 + lane];
        wave_topk_insert(bv, bi, __int_as_float(p.x), p.y, lane);
    }
    sbuf[w * 64 + lane] = make_int2(__float_as_int(bv), bi);
    __syncthreads();

    if (w == 0) {
#pragma unroll 1
        for (int q = 1; q < 4; ++q) {
            int2 p = sbuf[q * 64 + lane];
            wave_topk_insert(bv, bi, __int_as_float(p.x), p.y, lane);
        }
        cand2[((size_t)b * 16 + bk) * 64 + lane] = make_int2(__float_as_int(bv), bi);
    }
}

// stage B: 8 blocks, 4 waves each -> 16 lists -> final 64 indices
__global__ __launch_bounds__(256) void topk_merge_k2b(
    const int2* __restrict__ cand2, int* __restrict__ out)
{
    __shared__ int2 sbuf[4 * 64];
    int b = blockIdx.x;
    int t = threadIdx.x;
    int w = t >> 6, lane = t & 63;
    const int2* cb = cand2 + (size_t)b * 16 * 64;

    int2 p0 = cb[(size_t)(w * 4) * 64 + lane];   // sorted list -> valid buffer init
    float bv = __int_as_float(p0.x);
    int   bi = p0.y;
#pragma unroll 1
    for (int q = 1; q < 4; ++q) {
        int2 p = cb[(size_t)(w * 4 + q) * 64 + lane];
        wave_topk_insert(bv, bi, __int_as_float(p.x), p.y, lane);
    }
    sbuf[w * 64 + lane] = make_int2(__float_as_int(bv), bi);
    __syncthreads();

    if (w == 0) {
#pragma unroll 1
        for (int q = 1; q < 4; ++q) {
            int2 p = sbuf[q * 64 + lane];
            wave_topk_insert(bv, bi, __int_as_float(p.x), p.y, lane);
        }
        out[b * K_OUT + lane] = bi;   // rank = lane (sorted desc, ties index asc)
    }
}

extern "C" void kernel_launch(void* const* d_in, const int* in_sizes, int n_in,
                              void* d_out, int out_size, void* d_ws, size_t ws_size,
                              hipStream_t stream) {
    const float* X  = (const float*)d_in[0];
    const float* W1 = (const float*)d_in[2];
    const float* b1 = (const float*)d_in[3];
    const float* W2 = (const float*)d_in[4];
    const float* b2 = (const float*)d_in[5];
    const float* W3 = (const float*)d_in[6];
    const float* b3 = (const float*)d_in[7];

    // choose points-per-wave (multiple of 256) so candidate buffers fit d_ws
    int ppw = 512;
    int bx, lpb;
    for (;;) {
        int wpb = (NPTS + ppw - 1) / ppw;
        bx = (wpb + 3) / 4;
        lpb = bx * 4;
        size_t need = (size_t)NBATCH * lpb * 64 * sizeof(int2)
                    + (size_t)NBATCH * 16 * 64 * sizeof(int2);
        if (need <= ws_size || ppw >= NPTS) break;
        ppw += 512;
    }

    int2* cand  = (int2*)d_ws;                       // NBATCH * lpb * 64 entries
    int2* cand2 = cand + (size_t)NBATCH * lpb * 64;  // NBATCH * 16 * 64 entries
    int*  out   = (int*)d_out;

    mlp_score_topk_k1<<<dim3(bx, NBATCH), 256, 0, stream>>>(X, W1, b1, W2, b2, W3, b3, cand, ppw);
    topk_merge_k2a<<<dim3(16, NBATCH), 256, 0, stream>>>(cand, cand2, lpb);
    topk_merge_k2b<<<dim3(NBATCH), 256, 0, stream>>>(cand2, out);
}

// Round 3
// 191.370 us; speedup vs baseline: 4.2367x; 4.2367x over previous
//
#include <hip/hip_runtime.h>
#include <math.h>

#define NPTS 400000
#define NBATCH 8
#define K_OUT 64
#define IDX_SENTINEL 0x7fffffff

// wbuf layout (floats): [0..511] W1^T [c][o]; [512..639] W2^T [c][o];
// [640..655] b1; [656..663] b2; [664..671] W3; [672] b3
#define WB_W2 512
#define WB_B1 640
#define WB_B2 656
#define WB_W3 664
#define WB_B3 672

// comparator: (value desc, index asc) — matches jax.lax.top_k tie-breaking
__device__ __forceinline__ bool better(float av, int ai, float bv, int bi) {
    return (av > bv) || (av == bv && ai < bi);
}

__device__ __forceinline__ void cmp_swap(float& v, int& i, int j, bool keepBetter) {
    float ov = __shfl_xor(v, j);
    int   oi = __shfl_xor(i, j);
    bool ob = better(ov, oi, v, i);
    if (keepBetter ? ob : !ob) { v = ov; i = oi; }
}

// Maintain per-wave top-64 (1 entry/lane, sorted descending by comparator).
__device__ __forceinline__ void wave_topk_insert(float& bv, int& bi, float nv, int ni, int lane) {
    float tv = __shfl(bv, 63);
    int   ti = __shfl(bi, 63);
    if (__ballot(better(nv, ni, tv, ti)) == 0ULL) return;
#pragma unroll
    for (int k = 2; k <= 64; k <<= 1) {
#pragma unroll
        for (int j = k >> 1; j > 0; j >>= 1) {
            bool keepBetter = (((lane & k) == 0) == ((lane & j) == 0));
            cmp_swap(nv, ni, j, keepBetter);
        }
    }
    float rv = __shfl(nv, lane ^ 63);
    int   ri = __shfl(ni, lane ^ 63);
    if (better(rv, ri, bv, bi)) { bv = rv; bi = ri; }
#pragma unroll
    for (int j = 32; j > 0; j >>= 1) cmp_swap(bv, bi, j, (lane & j) == 0);
}

__global__ __launch_bounds__(256) void prep_weights(
    const float* __restrict__ W1, const float* __restrict__ b1,
    const float* __restrict__ W2, const float* __restrict__ b2,
    const float* __restrict__ W3, const float* __restrict__ b3,
    float* __restrict__ wbuf)
{
    int t = threadIdx.x;
    for (int i = t; i < 512; i += 256) wbuf[i] = W1[(i & 15) * 32 + (i >> 4)];
    if (t < 128) wbuf[WB_W2 + t] = W2[(t & 7) * 16 + (t >> 3)];
    if (t < 16)       wbuf[WB_B1 + t] = b1[t];
    else if (t < 24)  wbuf[WB_B2 + (t - 16)] = b2[t - 16];
    else if (t < 32)  wbuf[WB_W3 + (t - 24)] = W3[t - 24];
    else if (t == 32) wbuf[WB_B3] = b3[0];
}

__global__ __launch_bounds__(256, 4) void mlp_score_topk_k1(
    const float* __restrict__ X, const float* __restrict__ wb,
    int2* __restrict__ cand, int ppw)
{
    int t = threadIdx.x;
    int b = blockIdx.y;
    int wave = blockIdx.x * 4 + (t >> 6);
    int lane = t & 63;
    const float* Xb = X + (size_t)b * 32 * NPTS;

    float bv = -INFINITY;
    int   bi = IDX_SENTINEL;

    int riters = ppw >> 8;           // 256 points per r-iter
    int waveStart = wave * ppw;

#pragma unroll 1
    for (int r = 0; r < riters; ++r) {
        int n = waveStart + r * 256 + lane * 4;   // quad start; NPTS % 4 == 0
        float z0 = -INFINITY, z1 = -INFINITY, z2 = -INFINITY, z3 = -INFINITY;
        bool valid = (n < NPTS);
        if (valid) {
            float4 a1[16];
#pragma unroll
            for (int o = 0; o < 16; ++o) a1[o] = make_float4(0.f, 0.f, 0.f, 0.f);
            // layer 1 (32->16): channel blocks of 4; weights come in as s_loads
#pragma unroll
            for (int cb = 0; cb < 8; ++cb) {
                float4 x[4];
#pragma unroll
                for (int j = 0; j < 4; ++j)
                    x[j] = *reinterpret_cast<const float4*>(Xb + (size_t)(cb * 4 + j) * NPTS + n);
#pragma unroll
                for (int j = 0; j < 4; ++j) {
                    int c = cb * 4 + j;
#pragma unroll
                    for (int o = 0; o < 16; ++o) {
                        float w = wb[c * 16 + o];          // uniform -> SGPR
                        a1[o].x = fmaf(w, x[j].x, a1[o].x);
                        a1[o].y = fmaf(w, x[j].y, a1[o].y);
                        a1[o].z = fmaf(w, x[j].z, a1[o].z);
                        a1[o].w = fmaf(w, x[j].w, a1[o].w);
                    }
                }
            }
            // layer 2 (16->8) + ReLU
            float4 a2[8];
#pragma unroll
            for (int o = 0; o < 8; ++o) a2[o] = make_float4(0.f, 0.f, 0.f, 0.f);
#pragma unroll
            for (int c = 0; c < 16; ++c) {
                float bb = wb[WB_B1 + c];
                float4 h = a1[c];
                h.x = fmaxf(h.x + bb, 0.f);
                h.y = fmaxf(h.y + bb, 0.f);
                h.z = fmaxf(h.z + bb, 0.f);
                h.w = fmaxf(h.w + bb, 0.f);
#pragma unroll
                for (int o = 0; o < 8; ++o) {
                    float w = wb[WB_W2 + c * 8 + o];       // uniform -> SGPR
                    a2[o].x = fmaf(w, h.x, a2[o].x);
                    a2[o].y = fmaf(w, h.y, a2[o].y);
                    a2[o].z = fmaf(w, h.z, a2[o].z);
                    a2[o].w = fmaf(w, h.w, a2[o].w);
                }
            }
            // layer 3 (8->1) + ReLU; softplus monotone -> rank by pre-activation
            float4 zacc = make_float4(0.f, 0.f, 0.f, 0.f);
#pragma unroll
            for (int c = 0; c < 8; ++c) {
                float bb = wb[WB_B2 + c];
                float4 h = a2[c];
                h.x = fmaxf(h.x + bb, 0.f);
                h.y = fmaxf(h.y + bb, 0.f);
                h.z = fmaxf(h.z + bb, 0.f);
                h.w = fmaxf(h.w + bb, 0.f);
                float w = wb[WB_W3 + c];
                zacc.x = fmaf(w, h.x, zacc.x);
                zacc.y = fmaf(w, h.y, zacc.y);
                zacc.z = fmaf(w, h.z, zacc.z);
                zacc.w = fmaf(w, h.w, zacc.w);
            }
            float b3v = wb[WB_B3];
            z0 = zacc.x + b3v; z1 = zacc.y + b3v; z2 = zacc.z + b3v; z3 = zacc.w + b3v;
        }
        int i0 = valid ? (n + 0) : IDX_SENTINEL;
        int i1 = valid ? (n + 1) : IDX_SENTINEL;
        int i2 = valid ? (n + 2) : IDX_SENTINEL;
        int i3 = valid ? (n + 3) : IDX_SENTINEL;
        wave_topk_insert(bv, bi, z0, i0, lane);
        wave_topk_insert(bv, bi, z1, i1, lane);
        wave_topk_insert(bv, bi, z2, i2, lane);
        wave_topk_insert(bv, bi, z3, i3, lane);
    }

    cand[((size_t)b * gridDim.x * 4 + wave) * 64 + lane] = make_int2(__float_as_int(bv), bi);
}

// stage A: 16 blocks/batch, 4 waves each -> reduce lpb lists to 16 lists/batch
__global__ __launch_bounds__(256) void topk_merge_k2a(
    const int2* __restrict__ cand, int2* __restrict__ cand2, int lpb)
{
    __shared__ int2 sbuf[4 * 64];
    int b = blockIdx.y;
    int bk = blockIdx.x;          // 0..15
    int t = threadIdx.x;
    int w = t >> 6, lane = t & 63;
    const int2* cb = cand + (size_t)b * lpb * 64;

    float bv = -INFINITY;
    int   bi = IDX_SENTINEL;
    int slot = bk * 4 + w;        // 0..63
#pragma unroll 1
    for (int L = slot; L < lpb; L += 64) {
        int2 p = cb[(size_t)L * 64 + lane];
        wave_topk_insert(bv, bi, __int_as_float(p.x), p.y, lane);
    }
    sbuf[w * 64 + lane] = make_int2(__float_as_int(bv), bi);
    __syncthreads();

    if (w == 0) {
#pragma unroll 1
        for (int q = 1; q < 4; ++q) {
            int2 p = sbuf[q * 64 + lane];
            wave_topk_insert(bv, bi, __int_as_float(p.x), p.y, lane);
        }
        cand2[((size_t)b * 16 + bk) * 64 + lane] = make_int2(__float_as_int(bv), bi);
    }
}

// stage B: 8 blocks -> 16 lists -> final 64 indices per batch
__global__ __launch_bounds__(256) void topk_merge_k2b(
    const int2* __restrict__ cand2, int* __restrict__ out)
{
    __shared__ int2 sbuf[4 * 64];
    int b = blockIdx.x;
    int t = threadIdx.x;
    int w = t >> 6, lane = t & 63;
    const int2* cb = cand2 + (size_t)b * 16 * 64;

    int2 p0 = cb[(size_t)(w * 4) * 64 + lane];
    float bv = __int_as_float(p0.x);
    int   bi = p0.y;
#pragma unroll 1
    for (int q = 1; q < 4; ++q) {
        int2 p = cb[(size_t)(w * 4 + q) * 64 + lane];
        wave_topk_insert(bv, bi, __int_as_float(p.x), p.y, lane);
    }
    sbuf[w * 64 + lane] = make_int2(__float_as_int(bv), bi);
    __syncthreads();

    if (w == 0) {
#pragma unroll 1
        for (int q = 1; q < 4; ++q) {
            int2 p = sbuf[q * 64 + lane];
            wave_topk_insert(bv, bi, __int_as_float(p.x), p.y, lane);
        }
        out[b * K_OUT + lane] = bi;   // rank = lane (sorted desc, ties index asc)
    }
}

extern "C" void kernel_launch(void* const* d_in, const int* in_sizes, int n_in,
                              void* d_out, int out_size, void* d_ws, size_t ws_size,
                              hipStream_t stream) {
    const float* X  = (const float*)d_in[0];
    const float* W1 = (const float*)d_in[2];
    const float* b1 = (const float*)d_in[3];
    const float* W2 = (const float*)d_in[4];
    const float* b2 = (const float*)d_in[5];
    const float* W3 = (const float*)d_in[6];
    const float* b3 = (const float*)d_in[7];

    // points-per-wave (multiple of 256) sized so candidate buffers fit d_ws
    int ppw = 256;
    int bx, lpb;
    for (;;) {
        int wpb = (NPTS + ppw - 1) / ppw;
        bx = (wpb + 3) / 4;
        lpb = bx * 4;
        size_t need = 4096
                    + (size_t)NBATCH * lpb * 64 * sizeof(int2)
                    + (size_t)NBATCH * 16 * 64 * sizeof(int2);
        if (need <= ws_size || ppw >= NPTS) break;
        ppw += 256;
    }

    float* wbuf = (float*)d_ws;                              // 673 floats
    int2*  cand = (int2*)((char*)d_ws + 4096);               // NBATCH * lpb * 64
    int2*  cand2 = cand + (size_t)NBATCH * lpb * 64;         // NBATCH * 16 * 64
    int*   out  = (int*)d_out;

    prep_weights<<<1, 256, 0, stream>>>(W1, b1, W2, b2, W3, b3, wbuf);
    mlp_score_topk_k1<<<dim3(bx, NBATCH), 256, 0, stream>>>(X, wbuf, cand, ppw);
    topk_merge_k2a<<<dim3(16, NBATCH), 256, 0, stream>>>(cand, cand2, lpb);
    topk_merge_k2b<<<dim3(NBATCH), 256, 0, stream>>>(cand2, out);
}